// Round 1
// baseline (484.922 us; speedup 1.0000x reference)
//
#include <hip/hip_runtime.h>

typedef unsigned short u16;
typedef __attribute__((ext_vector_type(8))) short  short8;
typedef __attribute__((ext_vector_type(8))) __bf16 bf16x8;
typedef __attribute__((ext_vector_type(4))) float  f32x4;

#define DEV __device__ __forceinline__

// B=8, N=1025, D=1024, H=16, Dh=64
#define BATCH 8
#define SEQ   1025
#define DMODEL 1024
#define NHEAD 16
#define DH    64
#define MROWS (BATCH*SEQ)      // 8200
#define VPAD  1152             // key padding for VT (18*64)

DEV float bf2f(u16 u) { union { unsigned int i; float f; } v; v.i = ((unsigned int)u) << 16; return v.f; }
DEV u16 f2bf(float f) {
  union { float f; unsigned int i; } v; v.f = f;
  unsigned int x = v.i;
  return (u16)((x + 0x7fffu + ((x >> 16) & 1u)) >> 16);  // RNE
}

DEV f32x4 mfma16(bf16x8 a, bf16x8 b, f32x4 c) {
  return __builtin_amdgcn_mfma_f32_16x16x32_bf16(a, b, c, 0, 0, 0);
}

DEV void gload_lds16(const void* g, void* s) {
  __builtin_amdgcn_global_load_lds(
      (const __attribute__((address_space(1))) void*)g,
      (__attribute__((address_space(3))) void*)s, 16, 0, 0);
}

// ---------------- prep kernels ----------------

__global__ void cast_x_kernel(const float* __restrict__ in, u16* __restrict__ out, int n8) {
  int i = blockIdx.x * blockDim.x + threadIdx.x;
  if (i >= n8) return;
  const float4* p = (const float4*)in + (size_t)i * 2;
  float4 a = p[0], b = p[1];
  short8 o;
  o[0] = (short)f2bf(a.x); o[1] = (short)f2bf(a.y); o[2] = (short)f2bf(a.z); o[3] = (short)f2bf(a.w);
  o[4] = (short)f2bf(b.x); o[5] = (short)f2bf(b.y); o[6] = (short)f2bf(b.z); o[7] = (short)f2bf(b.w);
  *(short8*)(out + (size_t)i * 8) = o;
}

// transpose+cast weights: WT[n][k] = w[k][n], bf16, K-major
__global__ void wt_transpose(const float* __restrict__ wq, const float* __restrict__ wk,
                             const float* __restrict__ wv, const float* __restrict__ wo,
                             u16* __restrict__ wtqkv, u16* __restrict__ wtout) {
  __shared__ float tile[64][65];
  int z = blockIdx.z;
  const float* src = (z == 0) ? wq : (z == 1) ? wk : (z == 2) ? wv : wo;
  int k0 = blockIdx.x * 64, n0 = blockIdx.y * 64;
  int c = threadIdx.x & 63, rq = threadIdx.x >> 6;
#pragma unroll
  for (int p = 0; p < 16; ++p) {
    int r = p * 4 + rq;                       // k-local
    tile[r][c] = src[(size_t)(k0 + r) * 1024 + n0 + c];
  }
  __syncthreads();
  u16* dst = (z < 3) ? (wtqkv + (size_t)z * 1024 * 1024) : wtout;
#pragma unroll
  for (int p = 0; p < 16; ++p) {
    int r = p * 4 + rq;                       // n-local
    dst[(size_t)(n0 + r) * 1024 + k0 + c] = f2bf(tile[c][r]);
  }
}

__global__ void rope_table_kernel(float* __restrict__ cost, float* __restrict__ sint) {
  int i = blockIdx.x * blockDim.x + threadIdx.x;
  if (i >= 1024 * 32) return;
  int pos = i >> 5, d = i & 31;
  float inv = powf(10000.0f, -(float)d / 32.0f);
  float ang = (float)pos * inv;
  cost[i] = cosf(ang);
  sint[i] = sinf(ang);
}

// ---------------- 128x128 bf16 MFMA GEMM (m97 structure) ----------------
// A[M][1024] bf16 row-major, Bw[N][1024] bf16 K-major (= W^T). C row-major ldC.
template <int F32OUT>
__global__ __launch_bounds__(256) void gemm128(const u16* __restrict__ A,
    const u16* __restrict__ Bw, void* __restrict__ Cout,
    const float* __restrict__ bias, int Mrows, int ldC) {
  __shared__ char smem[32768];   // A tile 16KB | B tile 16KB, linear [128][64] bf16
  const int t = threadIdx.x;
  const int wid = t >> 6, lane = t & 63;
  const int l4 = lane >> 4, l15 = lane & 15;
  const int wr = wid >> 1, wc = wid & 1;
  const long rowA0 = (long)blockIdx.x * 128;
  const long rowB0 = (long)blockIdx.y * 128;

  f32x4 acc[4][4];
#pragma unroll
  for (int m = 0; m < 4; ++m)
#pragma unroll
    for (int n = 0; n < 4; ++n) { f32x4 z = {0.f,0.f,0.f,0.f}; acc[m][n] = z; }

  const int srow = t >> 3;        // 0..31
  const int scol = (t & 7) * 8;   // bf16 elems

  for (int k0 = 0; k0 < 1024; k0 += 64) {
    __syncthreads();
#pragma unroll
    for (int i = 0; i < 4; ++i) {
      const u16* ga = A  + (rowA0 + i * 32 + srow) * 1024 + k0 + scol;
      gload_lds16(ga, smem + i * 4096 + wid * 1024);
      const u16* gb = Bw + (rowB0 + i * 32 + srow) * 1024 + k0 + scol;
      gload_lds16(gb, smem + 16384 + i * 4096 + wid * 1024);
    }
    __syncthreads();

    bf16x8 af[4][2], bfr[4][2];
#pragma unroll
    for (int m = 0; m < 4; ++m)
#pragma unroll
      for (int kk = 0; kk < 2; ++kk)
        af[m][kk] = *(const bf16x8*)(smem + (wr * 64 + m * 16 + l15) * 128 + kk * 64 + l4 * 16);
#pragma unroll
    for (int n = 0; n < 4; ++n)
#pragma unroll
      for (int kk = 0; kk < 2; ++kk)
        bfr[n][kk] = *(const bf16x8*)(smem + 16384 + (wc * 64 + n * 16 + l15) * 128 + kk * 64 + l4 * 16);

#pragma unroll
    for (int m = 0; m < 4; ++m)
#pragma unroll
      for (int n = 0; n < 4; ++n)
#pragma unroll
        for (int kk = 0; kk < 2; ++kk)
          acc[m][n] = mfma16(af[m][kk], bfr[n][kk], acc[m][n]);
  }

#pragma unroll
  for (int m = 0; m < 4; ++m)
#pragma unroll
    for (int rg = 0; rg < 4; ++rg) {
      long row = rowA0 + wr * 64 + m * 16 + l4 * 4 + rg;
      if (row >= Mrows) continue;
#pragma unroll
      for (int n = 0; n < 4; ++n) {
        long col = rowB0 + wc * 64 + n * 16 + l15;
        float val = acc[m][n][rg];
        if (F32OUT) ((float*)Cout)[row * ldC + col] = val + bias[col];
        else        ((u16*) Cout)[row * ldC + col] = f2bf(val);
      }
    }
}

// ---------------- RoPE + scale + head-split for Q,K ----------------
// cqkv: [8200][3072] bf16 (q|k|v). Writes Qh/Kh as [bh][n][64] bf16.
__global__ void rope_qk(const u16* __restrict__ cq, const float* __restrict__ qb,
                        const float* __restrict__ cost, const float* __restrict__ sint,
                        u16* __restrict__ Qh, u16* __restrict__ Kh) {
  int idx = blockIdx.x * 256 + threadIdx.x;   // (b*1025+n)*16 + h
  if (idx >= MROWS * NHEAD) return;
  int h = idx & 15, row = idx >> 4;
  int b = row / SEQ, n = row - b * SEQ;
  const u16* src = cq + (size_t)row * 3072 + h * 64;
  size_t dbase = ((size_t)(b * 16 + h) * SEQ + n) * 64;
  bool dorope = (n > 0);
  const float* ct = cost + (size_t)(n - 1) * 32;
  const float* st = sint + (size_t)(n - 1) * 32;
#pragma unroll
  for (int i = 0; i < 4; ++i) {
    short8 qlo = *(const short8*)(src + i * 8);
    short8 qhi = *(const short8*)(src + 32 + i * 8);
    short8 klo = *(const short8*)(src + 1024 + i * 8);
    short8 khi = *(const short8*)(src + 1024 + 32 + i * 8);
    short8 oqlo, oqhi, oklo, okhi;
#pragma unroll
    for (int j = 0; j < 8; ++j) {
      int d = i * 8 + j;
      float q1 = bf2f((u16)qlo[j]) + qb[h * 64 + d];
      float q2 = bf2f((u16)qhi[j]) + qb[h * 64 + 32 + d];
      float k1 = bf2f((u16)klo[j]);
      float k2 = bf2f((u16)khi[j]);
      float c = dorope ? ct[d] : 1.0f;
      float s = dorope ? st[d] : 0.0f;
      oqlo[j] = (short)f2bf((q1 * c - q2 * s) * 0.125f);  // scale folded into Q
      oqhi[j] = (short)f2bf((q1 * s + q2 * c) * 0.125f);
      oklo[j] = (short)f2bf(k1 * c - k2 * s);
      okhi[j] = (short)f2bf(k1 * s + k2 * c);
    }
    *(short8*)(Qh + dbase + i * 8)      = oqlo;
    *(short8*)(Qh + dbase + 32 + i * 8) = oqhi;
    *(short8*)(Kh + dbase + i * 8)      = oklo;
    *(short8*)(Kh + dbase + 32 + i * 8) = okhi;
  }
}

// ---------------- V: bias + per-head transpose to VT[bh][d][keypad=1152] ----------------
__global__ void v_transpose(const u16* __restrict__ cq, const float* __restrict__ vb,
                            u16* __restrict__ VTh) {
  __shared__ float tile[64][65];
  int bh = blockIdx.y, b = bh >> 4, h = bh & 15;
  int n0 = blockIdx.x * 64;
  int c = threadIdx.x & 63, rq = threadIdx.x >> 6;
#pragma unroll
  for (int p = 0; p < 16; ++p) {
    int r = p * 4 + rq;
    int n = n0 + r;
    float v = 0.f;
    if (n < SEQ) v = bf2f(cq[(size_t)(b * SEQ + n) * 3072 + 2048 + h * 64 + c]) + vb[h * 64 + c];
    tile[r][c] = v;
  }
  __syncthreads();
#pragma unroll
  for (int p = 0; p < 16; ++p) {
    int d = p * 4 + rq;
    VTh[((size_t)bh * 64 + d) * VPAD + n0 + c] = f2bf(tile[c][d]);
  }
}

// ---------------- flash attention: 4 waves x 16 q-rows, KT=64 ----------------
__global__ __launch_bounds__(256) void attn64(const u16* __restrict__ Qh,
    const u16* __restrict__ Kh, const u16* __restrict__ VTh,
    u16* __restrict__ xattn) {
  __shared__ char plds[8192];     // 4 waves x 16x64 bf16 P tiles (XOR-swizzled)
  const int qt = blockIdx.x, bh = blockIdx.y;
  const int b = bh >> 4, h = bh & 15;
  const int t = threadIdx.x, w = t >> 6, lane = t & 63;
  const int l4 = lane >> 4, l15 = lane & 15;
  const u16* Qb = Qh + (size_t)bh * (SEQ * 64);
  const u16* Kb = Kh + (size_t)bh * (SEQ * 64);
  const u16* Vb = VTh + (size_t)bh * (64 * VPAD);
  const int q0 = qt * 64 + w * 16;

  bf16x8 aq0, aq1;
  {
    int qr = q0 + l15; if (qr > 1024) qr = 1024;
    aq0 = *(const bf16x8*)(Qb + (size_t)qr * 64 + l4 * 8);
    aq1 = *(const bf16x8*)(Qb + (size_t)qr * 64 + 32 + l4 * 8);
  }

  f32x4 o[4];
#pragma unroll
  for (int n = 0; n < 4; ++n) { f32x4 z = {0.f,0.f,0.f,0.f}; o[n] = z; }
  float mrow[4] = {-1e30f, -1e30f, -1e30f, -1e30f};
  float lsum[4] = {0.f, 0.f, 0.f, 0.f};
  char* pw = plds + w * 2048;

  for (int kt = 0; kt < 17; ++kt) {
    const int kb = kt * 64;
    f32x4 s[4];
#pragma unroll
    for (int tt = 0; tt < 4; ++tt) {
      int kr = kb + tt * 16 + l15; if (kr > 1024) kr = 1024;
      bf16x8 bk0 = *(const bf16x8*)(Kb + (size_t)kr * 64 + l4 * 8);
      bf16x8 bk1 = *(const bf16x8*)(Kb + (size_t)kr * 64 + 32 + l4 * 8);
      f32x4 z = {0.f,0.f,0.f,0.f};
      z = mfma16(aq0, bk0, z);
      z = mfma16(aq1, bk1, z);
      s[tt] = z;
    }
    // mask invalid keys
#pragma unroll
    for (int tt = 0; tt < 4; ++tt)
      if (kb + tt * 16 + l15 >= SEQ) { s[tt][0] = -1e30f; s[tt][1] = -1e30f; s[tt][2] = -1e30f; s[tt][3] = -1e30f; }

    float mb[4];
#pragma unroll
    for (int r = 0; r < 4; ++r)
      mb[r] = fmaxf(fmaxf(s[0][r], s[1][r]), fmaxf(s[2][r], s[3][r]));
#pragma unroll
    for (int msk = 1; msk < 16; msk <<= 1)
#pragma unroll
      for (int r = 0; r < 4; ++r)
        mb[r] = fmaxf(mb[r], __shfl_xor(mb[r], msk));

    float alpha[4], rs[4];
#pragma unroll
    for (int r = 0; r < 4; ++r) {
      float mn = fmaxf(mrow[r], mb[r]);
      alpha[r] = __expf(mrow[r] - mn);
      mrow[r] = mn;
      rs[r] = 0.f;
    }
#pragma unroll
    for (int tt = 0; tt < 4; ++tt)
#pragma unroll
      for (int r = 0; r < 4; ++r) {
        float p = __expf(s[tt][r] - mrow[r]);
        s[tt][r] = p;
        rs[r] += p;
      }
#pragma unroll
    for (int msk = 1; msk < 16; msk <<= 1)
#pragma unroll
      for (int r = 0; r < 4; ++r)
        rs[r] += __shfl_xor(rs[r], msk);
#pragma unroll
    for (int r = 0; r < 4; ++r)
      lsum[r] = lsum[r] * alpha[r] + rs[r];
#pragma unroll
    for (int n = 0; n < 4; ++n)
#pragma unroll
      for (int r = 0; r < 4; ++r)
        o[n][r] *= alpha[r];

    // P -> LDS (bf16, XOR swizzle to kill stride-128B bank conflicts)
#pragma unroll
    for (int tt = 0; tt < 4; ++tt)
#pragma unroll
      for (int r = 0; r < 4; ++r) {
        int prow = l4 * 4 + r, pcol = tt * 16 + l15;
        *(u16*)(pw + prow * 128 + ((pcol * 2) ^ ((prow & 7) << 4))) = f2bf(s[tt][r]);
      }

    // PV: A = P (via LDS), B = V^T rows (contiguous keys)
#pragma unroll
    for (int kk = 0; kk < 2; ++kk) {
      bf16x8 pa = *(const bf16x8*)(pw + l15 * 128 + ((kk * 64 + l4 * 16) ^ ((l15 & 7) << 4)));
      const int kidx = kb + kk * 32 + l4 * 8;
#pragma unroll
      for (int n = 0; n < 4; ++n) {
        bf16x8 bv = *(const bf16x8*)(Vb + (size_t)(n * 16 + l15) * VPAD + kidx);
        o[n] = mfma16(pa, bv, o[n]);
      }
    }
  }

#pragma unroll
  for (int n = 0; n < 4; ++n)
#pragma unroll
    for (int rg = 0; rg < 4; ++rg) {
      int qrow = q0 + l4 * 4 + rg;
      if (qrow < SEQ)
        xattn[(size_t)(b * SEQ + qrow) * 1024 + h * 64 + n * 16 + l15] = f2bf(o[n][rg] / lsum[rg]);
    }
}

// ---------------- launch ----------------

extern "C" void kernel_launch(void* const* d_in, const int* in_sizes, int n_in,
                              void* d_out, int out_size, void* d_ws, size_t ws_size,
                              hipStream_t stream) {
  const float* x      = (const float*)d_in[0];
  const float* wq     = (const float*)d_in[1];
  const float* wk     = (const float*)d_in[2];
  const float* wv     = (const float*)d_in[3];
  const float* q_bias = (const float*)d_in[4];
  const float* v_bias = (const float*)d_in[5];
  const float* w_out  = (const float*)d_in[6];
  const float* b_out  = (const float*)d_in[7];

  char* ws = (char*)d_ws;
  size_t off = 0;
  auto alc = [&](size_t bytes) { size_t r = off; off += (bytes + 255) & ~(size_t)255; return r; };

  u16*  x_bf  = (u16*)(ws + alc((size_t)MROWS * 1024 * 2));
  u16*  wtqkv = (u16*)(ws + alc((size_t)3072 * 1024 * 2));
  u16*  wtout = (u16*)(ws + alc((size_t)1024 * 1024 * 2));
  u16*  xattn = (u16*)(ws + alc((size_t)MROWS * 1024 * 2));
  u16*  cqkv  = (u16*)(ws + alc((size_t)MROWS * 3072 * 2));
  u16*  Qhp   = (u16*)(ws + alc((size_t)128 * SEQ * 64 * 2));
  u16*  Khp   = (u16*)(ws + alc((size_t)128 * SEQ * 64 * 2));
  u16*  VThp  = (u16*)(ws + alc((size_t)128 * 64 * VPAD * 2));
  float* cost = (float*)(ws + alc((size_t)1024 * 32 * 4));
  float* sint = (float*)(ws + alc((size_t)1024 * 32 * 4));
  (void)ws_size; (void)in_sizes; (void)n_in; (void)out_size;

  // 1. cast x to bf16
  cast_x_kernel<<<4100, 256, 0, stream>>>(x, x_bf, MROWS * 1024 / 8);
  // 2. weights -> K-major bf16
  wt_transpose<<<dim3(16, 16, 4), 256, 0, stream>>>(wq, wk, wv, w_out, wtqkv, wtout);
  // 3. rope tables
  rope_table_kernel<<<128, 256, 0, stream>>>(cost, sint);
  // 4. fused QKV projection: [8200x1024] @ [1024x3072]
  gemm128<0><<<dim3(65, 24), 256, 0, stream>>>(x_bf, wtqkv, (void*)cqkv, nullptr, MROWS, 3072);
  // 5. rope + scale + head split for Q,K
  rope_qk<<<513, 256, 0, stream>>>(cqkv, q_bias, cost, sint, Qhp, Khp);
  // 6. V bias + per-head transpose (zero-padded keys)
  v_transpose<<<dim3(18, 128), 256, 0, stream>>>(cqkv, v_bias, VThp);
  // 7. flash attention
  attn64<<<dim3(17, 128), 256, 0, stream>>>(Qhp, Khp, VThp, xattn);
  // 8. output projection + bias -> d_out (fp32)
  gemm128<1><<<dim3(65, 8), 256, 0, stream>>>(xattn, wtout, d_out, b_out, MROWS, 1024);
}

// Round 2
// 357.011 us; speedup vs baseline: 1.3583x; 1.3583x over previous
//
#include <hip/hip_runtime.h>

typedef unsigned short u16;
typedef __attribute__((ext_vector_type(8))) short  short8;
typedef __attribute__((ext_vector_type(8))) __bf16 bf16x8;
typedef __attribute__((ext_vector_type(4))) float  f32x4;

#define DEV __device__ __forceinline__

// B=8, N=1025, D=1024, H=16, Dh=64
#define BATCH 8
#define SEQ   1025
#define DMODEL 1024
#define NHEAD 16
#define DH    64
#define MROWS (BATCH*SEQ)      // 8200
#define VPAD  1152             // key padding for VT
#define KROWS 1088             // padded K row stride (17*64)

DEV float bf2f(u16 u) { union { unsigned int i; float f; } v; v.i = ((unsigned int)u) << 16; return v.f; }
DEV u16 f2bf(float f) {
  union { float f; unsigned int i; } v; v.f = f;
  unsigned int x = v.i;
  return (u16)((x + 0x7fffu + ((x >> 16) & 1u)) >> 16);  // RNE
}

DEV f32x4 mfma16(bf16x8 a, bf16x8 b, f32x4 c) {
  return __builtin_amdgcn_mfma_f32_16x16x32_bf16(a, b, c, 0, 0, 0);
}

DEV void gload_lds16(const void* g, void* s) {
  __builtin_amdgcn_global_load_lds(
      (const __attribute__((address_space(1))) void*)g,
      (__attribute__((address_space(3))) void*)s, 16, 0, 0);
}

// ---------------- prep kernels ----------------

__global__ void cast_x_kernel(const float* __restrict__ in, u16* __restrict__ out, int n8) {
  int i = blockIdx.x * blockDim.x + threadIdx.x;
  if (i >= n8) return;
  const float4* p = (const float4*)in + (size_t)i * 2;
  float4 a = p[0], b = p[1];
  short8 o;
  o[0] = (short)f2bf(a.x); o[1] = (short)f2bf(a.y); o[2] = (short)f2bf(a.z); o[3] = (short)f2bf(a.w);
  o[4] = (short)f2bf(b.x); o[5] = (short)f2bf(b.y); o[6] = (short)f2bf(b.z); o[7] = (short)f2bf(b.w);
  *(short8*)(out + (size_t)i * 8) = o;
}

// transpose+cast weights: WT[n][k] = w[k][n], bf16, K-major
__global__ void wt_transpose(const float* __restrict__ wq, const float* __restrict__ wk,
                             const float* __restrict__ wv, const float* __restrict__ wo,
                             u16* __restrict__ wtqkv, u16* __restrict__ wtout) {
  __shared__ float tile[64][65];
  int z = blockIdx.z;
  const float* src = (z == 0) ? wq : (z == 1) ? wk : (z == 2) ? wv : wo;
  int k0 = blockIdx.x * 64, n0 = blockIdx.y * 64;
  int c = threadIdx.x & 63, rq = threadIdx.x >> 6;
#pragma unroll
  for (int p = 0; p < 16; ++p) {
    int r = p * 4 + rq;                       // k-local
    tile[r][c] = src[(size_t)(k0 + r) * 1024 + n0 + c];
  }
  __syncthreads();
  u16* dst = (z < 3) ? (wtqkv + (size_t)z * 1024 * 1024) : wtout;
#pragma unroll
  for (int p = 0; p < 16; ++p) {
    int r = p * 4 + rq;                       // n-local
    dst[(size_t)(n0 + r) * 1024 + k0 + c] = f2bf(tile[c][r]);
  }
}

__global__ void rope_table_kernel(float* __restrict__ cost, float* __restrict__ sint) {
  int i = blockIdx.x * blockDim.x + threadIdx.x;
  if (i >= 1024 * 32) return;
  int pos = i >> 5, d = i & 31;
  float inv = powf(10000.0f, -(float)d / 32.0f);
  float ang = (float)pos * inv;
  cost[i] = cosf(ang);
  sint[i] = sinf(ang);
}

// ---------------- 128x128 bf16 MFMA GEMM (m97 structure) ----------------
template <int F32OUT>
__global__ __launch_bounds__(256) void gemm128(const u16* __restrict__ A,
    const u16* __restrict__ Bw, void* __restrict__ Cout,
    const float* __restrict__ bias, int Mrows, int ldC) {
  __shared__ char smem[32768];   // A tile 16KB | B tile 16KB, linear [128][64] bf16
  const int t = threadIdx.x;
  const int wid = t >> 6, lane = t & 63;
  const int l4 = lane >> 4, l15 = lane & 15;
  const int wr = wid >> 1, wc = wid & 1;
  const long rowA0 = (long)blockIdx.x * 128;
  const long rowB0 = (long)blockIdx.y * 128;

  f32x4 acc[4][4];
#pragma unroll
  for (int m = 0; m < 4; ++m)
#pragma unroll
    for (int n = 0; n < 4; ++n) { f32x4 z = {0.f,0.f,0.f,0.f}; acc[m][n] = z; }

  const int srow = t >> 3;        // 0..31
  const int scol = (t & 7) * 8;   // bf16 elems

  for (int k0 = 0; k0 < 1024; k0 += 64) {
    __syncthreads();
#pragma unroll
    for (int i = 0; i < 4; ++i) {
      const u16* ga = A  + (rowA0 + i * 32 + srow) * 1024 + k0 + scol;
      gload_lds16(ga, smem + i * 4096 + wid * 1024);
      const u16* gb = Bw + (rowB0 + i * 32 + srow) * 1024 + k0 + scol;
      gload_lds16(gb, smem + 16384 + i * 4096 + wid * 1024);
    }
    __syncthreads();

    bf16x8 af[4][2], bfr[4][2];
#pragma unroll
    for (int m = 0; m < 4; ++m)
#pragma unroll
      for (int kk = 0; kk < 2; ++kk)
        af[m][kk] = *(const bf16x8*)(smem + (wr * 64 + m * 16 + l15) * 128 + kk * 64 + l4 * 16);
#pragma unroll
    for (int n = 0; n < 4; ++n)
#pragma unroll
      for (int kk = 0; kk < 2; ++kk)
        bfr[n][kk] = *(const bf16x8*)(smem + 16384 + (wc * 64 + n * 16 + l15) * 128 + kk * 64 + l4 * 16);

#pragma unroll
    for (int m = 0; m < 4; ++m)
#pragma unroll
      for (int n = 0; n < 4; ++n)
#pragma unroll
        for (int kk = 0; kk < 2; ++kk)
          acc[m][n] = mfma16(af[m][kk], bfr[n][kk], acc[m][n]);
  }

#pragma unroll
  for (int m = 0; m < 4; ++m)
#pragma unroll
    for (int rg = 0; rg < 4; ++rg) {
      long row = rowA0 + wr * 64 + m * 16 + l4 * 4 + rg;
      if (row >= Mrows) continue;
#pragma unroll
      for (int n = 0; n < 4; ++n) {
        long col = rowB0 + wc * 64 + n * 16 + l15;
        float val = acc[m][n][rg];
        if (F32OUT) ((float*)Cout)[row * ldC + col] = val + bias[col];
        else        ((u16*) Cout)[row * ldC + col] = f2bf(val);
      }
    }
}

// ---------------- RoPE + scale + head-split for Q,K ----------------
// cqkv: [8200][3072] bf16 (q|k|v). Q -> [bh][SEQ][64], K -> [bh][KROWS][64].
__global__ void rope_qk(const u16* __restrict__ cq, const float* __restrict__ qb,
                        const float* __restrict__ cost, const float* __restrict__ sint,
                        u16* __restrict__ Qh, u16* __restrict__ Kh) {
  int idx = blockIdx.x * 256 + threadIdx.x;   // (b*1025+n)*16 + h
  if (idx >= MROWS * NHEAD) return;
  int h = idx & 15, row = idx >> 4;
  int b = row / SEQ, n = row - b * SEQ;
  const u16* src = cq + (size_t)row * 3072 + h * 64;
  size_t dq = ((size_t)(b * 16 + h) * SEQ   + n) * 64;
  size_t dk = ((size_t)(b * 16 + h) * KROWS + n) * 64;
  bool dorope = (n > 0);
  const float* ct = cost + (size_t)(n - 1) * 32;
  const float* st = sint + (size_t)(n - 1) * 32;
#pragma unroll
  for (int i = 0; i < 4; ++i) {
    short8 qlo = *(const short8*)(src + i * 8);
    short8 qhi = *(const short8*)(src + 32 + i * 8);
    short8 klo = *(const short8*)(src + 1024 + i * 8);
    short8 khi = *(const short8*)(src + 1024 + 32 + i * 8);
    short8 oqlo, oqhi, oklo, okhi;
#pragma unroll
    for (int j = 0; j < 8; ++j) {
      int d = i * 8 + j;
      float q1 = bf2f((u16)qlo[j]) + qb[h * 64 + d];
      float q2 = bf2f((u16)qhi[j]) + qb[h * 64 + 32 + d];
      float k1 = bf2f((u16)klo[j]);
      float k2 = bf2f((u16)khi[j]);
      float c = dorope ? ct[d] : 1.0f;
      float s = dorope ? st[d] : 0.0f;
      oqlo[j] = (short)f2bf((q1 * c - q2 * s) * 0.125f);  // scale folded into Q
      oqhi[j] = (short)f2bf((q1 * s + q2 * c) * 0.125f);
      oklo[j] = (short)f2bf(k1 * c - k2 * s);
      okhi[j] = (short)f2bf(k1 * s + k2 * c);
    }
    *(short8*)(Qh + dq + i * 8)      = oqlo;
    *(short8*)(Qh + dq + 32 + i * 8) = oqhi;
    *(short8*)(Kh + dk + i * 8)      = oklo;
    *(short8*)(Kh + dk + 32 + i * 8) = okhi;
  }
}

// ---------------- V: bias + per-head transpose to VT[bh][d][VPAD] ----------------
__global__ void v_transpose(const u16* __restrict__ cq, const float* __restrict__ vb,
                            u16* __restrict__ VTh) {
  __shared__ float tile[64][65];
  int bh = blockIdx.y, b = bh >> 4, h = bh & 15;
  int n0 = blockIdx.x * 64;
  int c = threadIdx.x & 63, rq = threadIdx.x >> 6;
#pragma unroll
  for (int p = 0; p < 16; ++p) {
    int r = p * 4 + rq;
    int n = n0 + r;
    float v = 0.f;
    if (n < SEQ) v = bf2f(cq[(size_t)(b * SEQ + n) * 3072 + 2048 + h * 64 + c]) + vb[h * 64 + c];
    tile[r][c] = v;
  }
  __syncthreads();
#pragma unroll
  for (int p = 0; p < 16; ++p) {
    int d = p * 4 + rq;
    VTh[((size_t)bh * 64 + d) * VPAD + n0 + c] = f2bf(tile[c][d]);
  }
}

// ---------------- flash attention v2: 128 q-rows/block, LDS-staged K/V, 2-phase ----------------
// Stage 64 rows x 128B (chunk-XOR-swizzled) from global into LDS (linear dest,
// pre-swizzled per-lane SOURCE address -- global_load_lds writes base+lane*16).
DEV void stage_rows(const u16* __restrict__ g, size_t strideElems, char* lbase,
                    int wid, int lane) {
#pragma unroll
  for (int s = 0; s < 2; ++s) {
    int off = s * 4096 + wid * 1024 + lane * 16;
    int r = off >> 7, cs = (off >> 4) & 7;
    const u16* src = g + (size_t)r * strideElems + ((cs ^ (r & 7)) << 3);
    gload_lds16(src, lbase + s * 4096 + wid * 1024);
  }
}

__global__ __launch_bounds__(256, 3) void attn128(const u16* __restrict__ Qh,
    const u16* __restrict__ Kh, const u16* __restrict__ VTh,
    u16* __restrict__ xattn) {
  __shared__ char lds[49152];  // K dbuf 16K | V dbuf 16K | P 4x4K
  const int qt = blockIdx.x, bh = blockIdx.y;
  const int b = bh >> 4, h = bh & 15;
  const int t = threadIdx.x, w = t >> 6, lane = t & 63;
  const int l4 = lane >> 4, l15 = lane & 15;
  const u16* Qb = Qh + (size_t)bh * (SEQ * 64);
  const u16* Kb = Kh + (size_t)bh * (KROWS * 64);
  const u16* Vb = VTh + (size_t)bh * (64 * VPAD);
  const int q0 = qt * 128 + w * 32;

  bf16x8 aq[2][2];
#pragma unroll
  for (int m = 0; m < 2; ++m) {
    int qr = q0 + m * 16 + l15; if (qr > SEQ - 1) qr = SEQ - 1;
    aq[m][0] = *(const bf16x8*)(Qb + (size_t)qr * 64 + l4 * 8);
    aq[m][1] = *(const bf16x8*)(Qb + (size_t)qr * 64 + 32 + l4 * 8);
  }

  f32x4 o[2][4];
  float mrow[2][4], lsum[2][4];
#pragma unroll
  for (int m = 0; m < 2; ++m) {
#pragma unroll
    for (int n = 0; n < 4; ++n) { f32x4 z = {0.f,0.f,0.f,0.f}; o[m][n] = z; }
#pragma unroll
    for (int r = 0; r < 4; ++r) { mrow[m][r] = -1e30f; lsum[m][r] = 0.f; }
  }
  char* pw = lds + 32768 + w * 4096;

  // prologue: stage tile 0 into buf 0
  stage_rows(Kb, 64, lds, w, lane);
  stage_rows(Vb, VPAD, lds + 16384, w, lane);
  asm volatile("s_waitcnt vmcnt(0)" ::: "memory");
  __syncthreads();

  int cur = 0;
  for (int kt = 0; kt < 17; ++kt) {
    const int kb = kt * 64;
    // issue next-tile stage (overlaps with this tile's compute)
    if (kt < 16) {
      stage_rows(Kb + (size_t)(kb + 64) * 64, 64, lds + (cur ^ 1) * 8192, w, lane);
      stage_rows(Vb + (kb + 64), VPAD, lds + 16384 + (cur ^ 1) * 8192, w, lane);
    }
    const char* Kl = lds + cur * 8192;
    const char* Vl = lds + 16384 + cur * 8192;

    // QK^T: s[m][tt], q-row = q0+m*16+l4*4+reg, key = kb+tt*16+l15
    f32x4 s[2][4];
#pragma unroll
    for (int tt = 0; tt < 4; ++tt) {
      const int kr = tt * 16 + l15;
      const char* kp = Kl + kr * 128;
      bf16x8 bk0 = *(const bf16x8*)(kp + ((l4       ^ (kr & 7)) << 4));
      bf16x8 bk1 = *(const bf16x8*)(kp + (((4 + l4) ^ (kr & 7)) << 4));
#pragma unroll
      for (int m = 0; m < 2; ++m) {
        f32x4 z = {0.f,0.f,0.f,0.f};
        z = mfma16(aq[m][0], bk0, z);
        z = mfma16(aq[m][1], bk1, z);
        s[m][tt] = z;
      }
    }

#pragma unroll
    for (int m = 0; m < 2; ++m) {
      // mask invalid keys (key index depends only on l15 & tt)
#pragma unroll
      for (int tt = 0; tt < 4; ++tt)
        if (kb + tt * 16 + l15 >= SEQ) {
          s[m][tt][0] = -1e30f; s[m][tt][1] = -1e30f; s[m][tt][2] = -1e30f; s[m][tt][3] = -1e30f;
        }
      float mb[4];
#pragma unroll
      for (int r = 0; r < 4; ++r)
        mb[r] = fmaxf(fmaxf(s[m][0][r], s[m][1][r]), fmaxf(s[m][2][r], s[m][3][r]));
#pragma unroll
      for (int msk = 1; msk < 16; msk <<= 1)
#pragma unroll
        for (int r = 0; r < 4; ++r)
          mb[r] = fmaxf(mb[r], __shfl_xor(mb[r], msk));

      float alpha[4], rs[4];
#pragma unroll
      for (int r = 0; r < 4; ++r) {
        float mn = fmaxf(mrow[m][r], mb[r]);
        alpha[r] = __expf(mrow[m][r] - mn);
        mrow[m][r] = mn;
        rs[r] = 0.f;
      }
#pragma unroll
      for (int tt = 0; tt < 4; ++tt)
#pragma unroll
        for (int r = 0; r < 4; ++r) {
          float p = __expf(s[m][tt][r] - mrow[m][r]);
          s[m][tt][r] = p;
          rs[r] += p;
        }
#pragma unroll
      for (int msk = 1; msk < 16; msk <<= 1)
#pragma unroll
        for (int r = 0; r < 4; ++r)
          rs[r] += __shfl_xor(rs[r], msk);
#pragma unroll
      for (int r = 0; r < 4; ++r)
        lsum[m][r] = lsum[m][r] * alpha[r] + rs[r];
#pragma unroll
      for (int n = 0; n < 4; ++n)
#pragma unroll
        for (int r = 0; r < 4; ++r)
          o[m][n][r] *= alpha[r];

      // P -> LDS (bf16, XOR-swizzled rows of 128B)
#pragma unroll
      for (int tt = 0; tt < 4; ++tt) {
        int pcol2 = (tt * 16 + l15) * 2;
#pragma unroll
        for (int r = 0; r < 4; ++r) {
          int prow = m * 16 + l4 * 4 + r;
          *(u16*)(pw + prow * 128 + (pcol2 ^ ((prow & 7) << 4))) = f2bf(s[m][tt][r]);
        }
      }
    }

    // PV: o[m][n] += P[q][k] * VT[d][k]
#pragma unroll
    for (int kk = 0; kk < 2; ++kk) {
      bf16x8 pa[2];
#pragma unroll
      for (int m = 0; m < 2; ++m)
        pa[m] = *(const bf16x8*)(pw + (m * 16 + l15) * 128 + ((kk * 64 + l4 * 16) ^ ((l15 & 7) << 4)));
#pragma unroll
      for (int n = 0; n < 4; ++n) {
        const int vr = n * 16 + l15;
        bf16x8 bv = *(const bf16x8*)(Vl + vr * 128 + (((kk * 4 + l4) ^ (vr & 7)) << 4));
#pragma unroll
        for (int m = 0; m < 2; ++m)
          o[m][n] = mfma16(pa[m], bv, o[m][n]);
      }
    }

    asm volatile("s_waitcnt vmcnt(0)" ::: "memory");
    __syncthreads();
    cur ^= 1;
  }

#pragma unroll
  for (int m = 0; m < 2; ++m)
#pragma unroll
    for (int n = 0; n < 4; ++n)
#pragma unroll
      for (int rg = 0; rg < 4; ++rg) {
        int qrow = q0 + m * 16 + l4 * 4 + rg;
        if (qrow < SEQ)
          xattn[(size_t)(b * SEQ + qrow) * 1024 + h * 64 + n * 16 + l15] =
              f2bf(o[m][n][rg] / lsum[m][rg]);
      }
}

// ---------------- launch ----------------

extern "C" void kernel_launch(void* const* d_in, const int* in_sizes, int n_in,
                              void* d_out, int out_size, void* d_ws, size_t ws_size,
                              hipStream_t stream) {
  const float* x      = (const float*)d_in[0];
  const float* wq     = (const float*)d_in[1];
  const float* wk     = (const float*)d_in[2];
  const float* wv     = (const float*)d_in[3];
  const float* q_bias = (const float*)d_in[4];
  const float* v_bias = (const float*)d_in[5];
  const float* w_out  = (const float*)d_in[6];
  const float* b_out  = (const float*)d_in[7];

  char* ws = (char*)d_ws;
  size_t off = 0;
  auto alc = [&](size_t bytes) { size_t r = off; off += (bytes + 255) & ~(size_t)255; return r; };

  u16*  x_bf  = (u16*)(ws + alc((size_t)MROWS * 1024 * 2));
  u16*  wtqkv = (u16*)(ws + alc((size_t)3072 * 1024 * 2));
  u16*  wtout = (u16*)(ws + alc((size_t)1024 * 1024 * 2));
  u16*  xattn = (u16*)(ws + alc((size_t)MROWS * 1024 * 2));
  u16*  cqkv  = (u16*)(ws + alc((size_t)MROWS * 3072 * 2));
  u16*  Qhp   = (u16*)(ws + alc((size_t)128 * SEQ * 64 * 2));
  u16*  Khp   = (u16*)(ws + alc((size_t)128 * KROWS * 64 * 2));
  u16*  VThp  = (u16*)(ws + alc((size_t)128 * 64 * VPAD * 2));
  float* cost = (float*)(ws + alc((size_t)1024 * 32 * 4));
  float* sint = (float*)(ws + alc((size_t)1024 * 32 * 4));
  (void)ws_size; (void)in_sizes; (void)n_in; (void)out_size;

  // 1. cast x to bf16
  cast_x_kernel<<<4100, 256, 0, stream>>>(x, x_bf, MROWS * 1024 / 8);
  // 2. weights -> K-major bf16
  wt_transpose<<<dim3(16, 16, 4), 256, 0, stream>>>(wq, wk, wv, w_out, wtqkv, wtout);
  // 3. rope tables
  rope_table_kernel<<<128, 256, 0, stream>>>(cost, sint);
  // 4. fused QKV projection: [8200x1024] @ [1024x3072]
  gemm128<0><<<dim3(65, 24), 256, 0, stream>>>(x_bf, wtqkv, (void*)cqkv, nullptr, MROWS, 3072);
  // 5. rope + scale + head split for Q,K
  rope_qk<<<513, 256, 0, stream>>>(cqkv, q_bias, cost, sint, Qhp, Khp);
  // 6. V bias + per-head transpose (zero-padded keys)
  v_transpose<<<dim3(18, 128), 256, 0, stream>>>(cqkv, v_bias, VThp);
  // 7. flash attention (128 q-rows/block, LDS-staged K/V double-buffered)
  attn128<<<dim3(9, 128), 256, 0, stream>>>(Qhp, Khp, VThp, xattn);
  // 8. output projection + bias -> d_out (fp32)
  gemm128<1><<<dim3(65, 8), 256, 0, stream>>>(xattn, wtout, d_out, b_out, MROWS, 1024);
}

// Round 3
// 294.668 us; speedup vs baseline: 1.6457x; 1.2116x over previous
//
#include <hip/hip_runtime.h>

typedef unsigned short u16;
typedef __attribute__((ext_vector_type(8))) short  short8;
typedef __attribute__((ext_vector_type(8))) __bf16 bf16x8;
typedef __attribute__((ext_vector_type(4))) float  f32x4;

#define DEV __device__ __forceinline__

// B=8, N=1025, D=1024, H=16, Dh=64
#define BATCH 8
#define SEQ   1025
#define DMODEL 1024
#define NHEAD 16
#define DH    64
#define MROWS (BATCH*SEQ)      // 8200
#define VPAD  1152             // key padding for VT
#define KROWS 1088             // padded K row stride (17*64)

DEV float bf2f(u16 u) { union { unsigned int i; float f; } v; v.i = ((unsigned int)u) << 16; return v.f; }
DEV u16 f2bf(float f) {
  union { float f; unsigned int i; } v; v.f = f;
  unsigned int x = v.i;
  return (u16)((x + 0x7fffu + ((x >> 16) & 1u)) >> 16);  // RNE
}

DEV f32x4 mfma16(bf16x8 a, bf16x8 b, f32x4 c) {
  return __builtin_amdgcn_mfma_f32_16x16x32_bf16(a, b, c, 0, 0, 0);
}

DEV void gload_lds16(const void* g, void* s) {
  __builtin_amdgcn_global_load_lds(
      (const __attribute__((address_space(1))) void*)g,
      (__attribute__((address_space(3))) void*)s, 16, 0, 0);
}

DEV float exp2_fast(float x) { float r; asm("v_exp_f32 %0, %1" : "=v"(r) : "v"(x)); return r; }
DEV unsigned cvt_pk_bf16(float lo, float hi) {
  unsigned r;
  asm("v_cvt_pk_bf16_f32 %0, %1, %2" : "=v"(r) : "v"(lo), "v"(hi));
  return r;
}

// ---------------- prep kernels ----------------

__global__ void cast_x_kernel(const float* __restrict__ in, u16* __restrict__ out, int n8) {
  int i = blockIdx.x * blockDim.x + threadIdx.x;
  if (i >= n8) return;
  const float4* p = (const float4*)in + (size_t)i * 2;
  float4 a = p[0], b = p[1];
  short8 o;
  o[0] = (short)f2bf(a.x); o[1] = (short)f2bf(a.y); o[2] = (short)f2bf(a.z); o[3] = (short)f2bf(a.w);
  o[4] = (short)f2bf(b.x); o[5] = (short)f2bf(b.y); o[6] = (short)f2bf(b.z); o[7] = (short)f2bf(b.w);
  *(short8*)(out + (size_t)i * 8) = o;
}

// transpose+cast weights: WT[n][k] = w[k][n], bf16, K-major
__global__ void wt_transpose(const float* __restrict__ wq, const float* __restrict__ wk,
                             const float* __restrict__ wv, const float* __restrict__ wo,
                             u16* __restrict__ wtqkv, u16* __restrict__ wtout) {
  __shared__ float tile[64][65];
  int z = blockIdx.z;
  const float* src = (z == 0) ? wq : (z == 1) ? wk : (z == 2) ? wv : wo;
  int k0 = blockIdx.x * 64, n0 = blockIdx.y * 64;
  int c = threadIdx.x & 63, rq = threadIdx.x >> 6;
#pragma unroll
  for (int p = 0; p < 16; ++p) {
    int r = p * 4 + rq;                       // k-local
    tile[r][c] = src[(size_t)(k0 + r) * 1024 + n0 + c];
  }
  __syncthreads();
  u16* dst = (z < 3) ? (wtqkv + (size_t)z * 1024 * 1024) : wtout;
#pragma unroll
  for (int p = 0; p < 16; ++p) {
    int r = p * 4 + rq;                       // n-local
    dst[(size_t)(n0 + r) * 1024 + k0 + c] = f2bf(tile[c][r]);
  }
}

__global__ void rope_table_kernel(float* __restrict__ cost, float* __restrict__ sint) {
  int i = blockIdx.x * blockDim.x + threadIdx.x;
  if (i >= 1024 * 32) return;
  int pos = i >> 5, d = i & 31;
  float inv = powf(10000.0f, -(float)d / 32.0f);
  float ang = (float)pos * inv;
  cost[i] = cosf(ang);
  sint[i] = sinf(ang);
}

// ---------------- 128x128 bf16 MFMA GEMM (m97 structure) ----------------
template <int F32OUT>
__global__ __launch_bounds__(256) void gemm128(const u16* __restrict__ A,
    const u16* __restrict__ Bw, void* __restrict__ Cout,
    const float* __restrict__ bias, int Mrows, int ldC) {
  __shared__ char smem[32768];   // A tile 16KB | B tile 16KB, linear [128][64] bf16
  const int t = threadIdx.x;
  const int wid = t >> 6, lane = t & 63;
  const int l4 = lane >> 4, l15 = lane & 15;
  const int wr = wid >> 1, wc = wid & 1;
  const long rowA0 = (long)blockIdx.x * 128;
  const long rowB0 = (long)blockIdx.y * 128;

  f32x4 acc[4][4];
#pragma unroll
  for (int m = 0; m < 4; ++m)
#pragma unroll
    for (int n = 0; n < 4; ++n) { f32x4 z = {0.f,0.f,0.f,0.f}; acc[m][n] = z; }

  const int srow = t >> 3;        // 0..31
  const int scol = (t & 7) * 8;   // bf16 elems

  for (int k0 = 0; k0 < 1024; k0 += 64) {
    __syncthreads();
#pragma unroll
    for (int i = 0; i < 4; ++i) {
      const u16* ga = A  + (rowA0 + i * 32 + srow) * 1024 + k0 + scol;
      gload_lds16(ga, smem + i * 4096 + wid * 1024);
      const u16* gb = Bw + (rowB0 + i * 32 + srow) * 1024 + k0 + scol;
      gload_lds16(gb, smem + 16384 + i * 4096 + wid * 1024);
    }
    __syncthreads();

    bf16x8 af[4][2], bfr[4][2];
#pragma unroll
    for (int m = 0; m < 4; ++m)
#pragma unroll
      for (int kk = 0; kk < 2; ++kk)
        af[m][kk] = *(const bf16x8*)(smem + (wr * 64 + m * 16 + l15) * 128 + kk * 64 + l4 * 16);
#pragma unroll
    for (int n = 0; n < 4; ++n)
#pragma unroll
      for (int kk = 0; kk < 2; ++kk)
        bfr[n][kk] = *(const bf16x8*)(smem + 16384 + (wc * 64 + n * 16 + l15) * 128 + kk * 64 + l4 * 16);

#pragma unroll
    for (int m = 0; m < 4; ++m)
#pragma unroll
      for (int n = 0; n < 4; ++n)
#pragma unroll
        for (int kk = 0; kk < 2; ++kk)
          acc[m][n] = mfma16(af[m][kk], bfr[n][kk], acc[m][n]);
  }

#pragma unroll
  for (int m = 0; m < 4; ++m)
#pragma unroll
    for (int rg = 0; rg < 4; ++rg) {
      long row = rowA0 + wr * 64 + m * 16 + l4 * 4 + rg;
      if (row >= Mrows) continue;
#pragma unroll
      for (int n = 0; n < 4; ++n) {
        long col = rowB0 + wc * 64 + n * 16 + l15;
        float val = acc[m][n][rg];
        if (F32OUT) ((float*)Cout)[row * ldC + col] = val + bias[col];
        else        ((u16*) Cout)[row * ldC + col] = f2bf(val);
      }
    }
}

// ---------------- RoPE + scale + head-split for Q,K ----------------
// Q scale folds softmax scale (0.125) AND log2(e) so attention works in exp2 domain.
#define QSCALE (0.125f * 1.44269504088896341f)
__global__ void rope_qk(const u16* __restrict__ cq, const float* __restrict__ qb,
                        const float* __restrict__ cost, const float* __restrict__ sint,
                        u16* __restrict__ Qh, u16* __restrict__ Kh) {
  int idx = blockIdx.x * 256 + threadIdx.x;   // (b*1025+n)*16 + h
  if (idx >= MROWS * NHEAD) return;
  int h = idx & 15, row = idx >> 4;
  int b = row / SEQ, n = row - b * SEQ;
  const u16* src = cq + (size_t)row * 3072 + h * 64;
  size_t dq = ((size_t)(b * 16 + h) * SEQ   + n) * 64;
  size_t dk = ((size_t)(b * 16 + h) * KROWS + n) * 64;
  bool dorope = (n > 0);
  const float* ct = cost + (size_t)(n - 1) * 32;
  const float* st = sint + (size_t)(n - 1) * 32;
#pragma unroll
  for (int i = 0; i < 4; ++i) {
    short8 qlo = *(const short8*)(src + i * 8);
    short8 qhi = *(const short8*)(src + 32 + i * 8);
    short8 klo = *(const short8*)(src + 1024 + i * 8);
    short8 khi = *(const short8*)(src + 1024 + 32 + i * 8);
    short8 oqlo, oqhi, oklo, okhi;
#pragma unroll
    for (int j = 0; j < 8; ++j) {
      int d = i * 8 + j;
      float q1 = bf2f((u16)qlo[j]) + qb[h * 64 + d];
      float q2 = bf2f((u16)qhi[j]) + qb[h * 64 + 32 + d];
      float k1 = bf2f((u16)klo[j]);
      float k2 = bf2f((u16)khi[j]);
      float c = dorope ? ct[d] : 1.0f;
      float s = dorope ? st[d] : 0.0f;
      oqlo[j] = (short)f2bf((q1 * c - q2 * s) * QSCALE);
      oqhi[j] = (short)f2bf((q1 * s + q2 * c) * QSCALE);
      oklo[j] = (short)f2bf(k1 * c - k2 * s);
      okhi[j] = (short)f2bf(k1 * s + k2 * c);
    }
    *(short8*)(Qh + dq + i * 8)      = oqlo;
    *(short8*)(Qh + dq + 32 + i * 8) = oqhi;
    *(short8*)(Kh + dk + i * 8)      = oklo;
    *(short8*)(Kh + dk + 32 + i * 8) = okhi;
  }
}

// ---------------- V: bias + per-head transpose to VT[bh][d][VPAD] ----------------
__global__ void v_transpose(const u16* __restrict__ cq, const float* __restrict__ vb,
                            u16* __restrict__ VTh) {
  __shared__ float tile[64][65];
  int bh = blockIdx.y, b = bh >> 4, h = bh & 15;
  int n0 = blockIdx.x * 64;
  int c = threadIdx.x & 63, rq = threadIdx.x >> 6;
#pragma unroll
  for (int p = 0; p < 16; ++p) {
    int r = p * 4 + rq;
    int n = n0 + r;
    float v = 0.f;
    if (n < SEQ) v = bf2f(cq[(size_t)(b * SEQ + n) * 3072 + 2048 + h * 64 + c]) + vb[h * 64 + c];
    tile[r][c] = v;
  }
  __syncthreads();
#pragma unroll
  for (int p = 0; p < 16; ++p) {
    int d = p * 4 + rq;
    VTh[((size_t)bh * 64 + d) * VPAD + n0 + c] = f2bf(tile[c][d]);
  }
}

// ---------------- flash attention v3 ----------------
// Swapped QK^T (A=K, B=Q) so P rows are lane-local; in-register softmax; P to
// PV A-frags via cvt_pk + ds_bpermute (no P LDS); row sums via ones-column MFMA;
// defer-max; exp2 domain; K/V LDS double-buffered via global_load_lds.
DEV void stage_rows(const u16* __restrict__ g, size_t strideElems, char* lbase,
                    int wid, int lane) {
#pragma unroll
  for (int s = 0; s < 2; ++s) {
    int off = s * 4096 + wid * 1024 + lane * 16;
    int r = off >> 7, cs = (off >> 4) & 7;
    const u16* src = g + (size_t)r * strideElems + ((cs ^ (r & 7)) << 3);
    gload_lds16(src, lbase + s * 4096 + wid * 1024);
  }
}

__global__ __launch_bounds__(256, 4) void attn128(const u16* __restrict__ Qh,
    const u16* __restrict__ Kh, const u16* __restrict__ VTh,
    u16* __restrict__ xattn) {
  __shared__ char lds[32768];  // K dbuf 16K | V dbuf 16K
  // bijective XCD swizzle: 1152 blocks, 144 per XCD chunk
  const int wg = blockIdx.x;
  const int x = (wg & 7) * 144 + (wg >> 3);
  const int qt = x % 9, bh = x / 9;
  const int b = bh >> 4, h = bh & 15;
  const int t = threadIdx.x, w = t >> 6, lane = t & 63;
  const int l4 = lane >> 4, l15 = lane & 15;
  const u16* Qb = Qh + (size_t)bh * (SEQ * 64);
  const u16* Kb = Kh + (size_t)bh * (KROWS * 64);
  const u16* Vb = VTh + (size_t)bh * (64 * VPAD);
  const int q0 = qt * 128 + w * 32;
  const int srcb = l15 + ((l4 & 1) << 5);   // bpermute src lane (b=0); +16 for b=1
  const bool hi4 = (l4 >> 1) != 0;

  bf16x8 aq[2][2];
#pragma unroll
  for (int m = 0; m < 2; ++m) {
    int qr = q0 + m * 16 + l15; if (qr > SEQ - 1) qr = SEQ - 1;
    aq[m][0] = *(const bf16x8*)(Qb + (size_t)qr * 64 + l4 * 8);
    aq[m][1] = *(const bf16x8*)(Qb + (size_t)qr * 64 + 32 + l4 * 8);
  }
  bf16x8 ones;
  { union { unsigned u[4]; bf16x8 v; } ou;
    ou.u[0] = ou.u[1] = ou.u[2] = ou.u[3] = 0x3F803F80u; ones = ou.v; }

  f32x4 o[2][4], osum[2];
  float mrow[2];
#pragma unroll
  for (int m = 0; m < 2; ++m) {
#pragma unroll
    for (int n = 0; n < 4; ++n) { f32x4 z = {0.f,0.f,0.f,0.f}; o[m][n] = z; }
    f32x4 z = {0.f,0.f,0.f,0.f}; osum[m] = z;
    mrow[m] = -1e30f;
  }

  // prologue: stage tile 0 into buf 0
  stage_rows(Kb, 64, lds, w, lane);
  stage_rows(Vb, VPAD, lds + 16384, w, lane);
  asm volatile("s_waitcnt vmcnt(0)" ::: "memory");
  __syncthreads();

  int cur = 0;
  for (int kt = 0; kt < 17; ++kt) {
    const int kb = kt * 64;
    if (kt < 16) {
      stage_rows(Kb + (size_t)(kb + 64) * 64, 64, lds + (cur ^ 1) * 8192, w, lane);
      stage_rows(Vb + (kb + 64), VPAD, lds + 16384 + (cur ^ 1) * 8192, w, lane);
    }
    const char* Kl = lds + cur * 8192;
    const char* Vl = lds + 16384 + cur * 8192;

    // QK^T swapped: s[m][tt] = C[key][q]: q = l15, key = tt*16 + l4*4 + reg
    f32x4 s[2][4];
#pragma unroll
    for (int tt = 0; tt < 4; ++tt) {
      const int kr = tt * 16 + l15;
      const char* kp = Kl + kr * 128;
      bf16x8 bk0 = *(const bf16x8*)(kp + ((l4       ^ (kr & 7)) << 4));
      bf16x8 bk1 = *(const bf16x8*)(kp + (((4 + l4) ^ (kr & 7)) << 4));
#pragma unroll
      for (int m = 0; m < 2; ++m) {
        f32x4 z = {0.f,0.f,0.f,0.f};
        z = mfma16(bk0, aq[m][0], z);
        z = mfma16(bk1, aq[m][1], z);
        s[m][tt] = z;
      }
    }

    if (kt == 16) {   // mask invalid keys (only key 1024 valid in last tile)
#pragma unroll
      for (int m = 0; m < 2; ++m) {
        s[m][0][0] = (l4 == 0) ? s[m][0][0] : -1e30f;
        s[m][0][1] = -1e30f; s[m][0][2] = -1e30f; s[m][0][3] = -1e30f;
#pragma unroll
        for (int tt = 1; tt < 4; ++tt) {
          s[m][tt][0] = -1e30f; s[m][tt][1] = -1e30f; s[m][tt][2] = -1e30f; s[m][tt][3] = -1e30f;
        }
      }
    }

    // row max (row = q = l15): in-register over 16 + shfl over l4 groups
    float tmax[2];
#pragma unroll
    for (int m = 0; m < 2; ++m) {
      float a0 = fmaxf(fmaxf(s[m][0][0], s[m][0][1]), fmaxf(s[m][0][2], s[m][0][3]));
      float a1 = fmaxf(fmaxf(s[m][1][0], s[m][1][1]), fmaxf(s[m][1][2], s[m][1][3]));
      float a2 = fmaxf(fmaxf(s[m][2][0], s[m][2][1]), fmaxf(s[m][2][2], s[m][2][3]));
      float a3 = fmaxf(fmaxf(s[m][3][0], s[m][3][1]), fmaxf(s[m][3][2], s[m][3][3]));
      float tm = fmaxf(fmaxf(a0, a1), fmaxf(a2, a3));
      tm = fmaxf(tm, __shfl_xor(tm, 16));
      tm = fmaxf(tm, __shfl_xor(tm, 32));
      tmax[m] = tm;
    }

    // defer-max: rescale only when max grew past THR (log2 domain, P <= 2^8)
    int needR = (tmax[0] > mrow[0] + 8.0f) || (tmax[1] > mrow[1] + 8.0f);
    if (__any(needR)) {
#pragma unroll
      for (int m = 0; m < 2; ++m) {
        float mnew = fmaxf(mrow[m], tmax[m]);
        float alpha = exp2_fast(mrow[m] - mnew);
        mrow[m] = mnew;
        float al[4];
#pragma unroll
        for (int rg = 0; rg < 4; ++rg) al[rg] = __shfl(alpha, l4 * 4 + rg);
#pragma unroll
        for (int n = 0; n < 4; ++n)
#pragma unroll
          for (int rg = 0; rg < 4; ++rg) o[m][n][rg] *= al[rg];
#pragma unroll
        for (int rg = 0; rg < 4; ++rg) osum[m][rg] *= al[rg];
      }
    }

    // P = exp2(s - m), packed to bf16 pairs (quad (tt,l4) -> 2 u32)
    unsigned pk[2][4][2];
#pragma unroll
    for (int m = 0; m < 2; ++m)
#pragma unroll
      for (int tt = 0; tt < 4; ++tt) {
        float p0 = exp2_fast(s[m][tt][0] - mrow[m]);
        float p1 = exp2_fast(s[m][tt][1] - mrow[m]);
        float p2 = exp2_fast(s[m][tt][2] - mrow[m]);
        float p3 = exp2_fast(s[m][tt][3] - mrow[m]);
        pk[m][tt][0] = cvt_pk_bf16(p0, p1);
        pk[m][tt][1] = cvt_pk_bf16(p2, p3);
      }

    // PV (+ones rowsum): A-frag P[q=l15][k=l4*8+j] gathered via bpermute
#pragma unroll
    for (int kk = 0; kk < 2; ++kk) {
      bf16x8 pa[2];
#pragma unroll
      for (int m = 0; m < 2; ++m) {
        union { unsigned u[4]; bf16x8 v; } pu;
#pragma unroll
        for (int bb = 0; bb < 2; ++bb)
#pragma unroll
          for (int pr = 0; pr < 2; ++pr) {
            unsigned t0 = (unsigned)__shfl((int)pk[m][2 * kk][pr],     srcb + bb * 16);
            unsigned t1 = (unsigned)__shfl((int)pk[m][2 * kk + 1][pr], srcb + bb * 16);
            pu.u[bb * 2 + pr] = hi4 ? t1 : t0;
          }
        pa[m] = pu.v;
      }
#pragma unroll
      for (int n = 0; n < 4; ++n) {
        const int vr = n * 16 + l15;
        bf16x8 bv = *(const bf16x8*)(Vl + vr * 128 + (((kk * 4 + l4) ^ (vr & 7)) << 4));
#pragma unroll
        for (int m = 0; m < 2; ++m)
          o[m][n] = mfma16(pa[m], bv, o[m][n]);
      }
#pragma unroll
      for (int m = 0; m < 2; ++m)
        osum[m] = mfma16(pa[m], ones, osum[m]);
    }

    asm volatile("s_waitcnt vmcnt(0)" ::: "memory");
    __syncthreads();
    cur ^= 1;
  }

#pragma unroll
  for (int m = 0; m < 2; ++m)
#pragma unroll
    for (int n = 0; n < 4; ++n)
#pragma unroll
      for (int rg = 0; rg < 4; ++rg) {
        int qrow = q0 + m * 16 + l4 * 4 + rg;
        if (qrow < SEQ)
          xattn[(size_t)(b * SEQ + qrow) * 1024 + h * 64 + n * 16 + l15] =
              f2bf(o[m][n][rg] / osum[m][rg]);
      }
}

// ---------------- launch ----------------

extern "C" void kernel_launch(void* const* d_in, const int* in_sizes, int n_in,
                              void* d_out, int out_size, void* d_ws, size_t ws_size,
                              hipStream_t stream) {
  const float* x      = (const float*)d_in[0];
  const float* wq     = (const float*)d_in[1];
  const float* wk     = (const float*)d_in[2];
  const float* wv     = (const float*)d_in[3];
  const float* q_bias = (const float*)d_in[4];
  const float* v_bias = (const float*)d_in[5];
  const float* w_out  = (const float*)d_in[6];
  const float* b_out  = (const float*)d_in[7];

  char* ws = (char*)d_ws;
  size_t off = 0;
  auto alc = [&](size_t bytes) { size_t r = off; off += (bytes + 255) & ~(size_t)255; return r; };

  u16*  x_bf  = (u16*)(ws + alc((size_t)MROWS * 1024 * 2));
  u16*  wtqkv = (u16*)(ws + alc((size_t)3072 * 1024 * 2));
  u16*  wtout = (u16*)(ws + alc((size_t)1024 * 1024 * 2));
  u16*  xattn = (u16*)(ws + alc((size_t)MROWS * 1024 * 2));
  u16*  cqkv  = (u16*)(ws + alc((size_t)MROWS * 3072 * 2));
  u16*  Qhp   = (u16*)(ws + alc((size_t)128 * SEQ * 64 * 2));
  u16*  Khp   = (u16*)(ws + alc((size_t)128 * KROWS * 64 * 2));
  u16*  VThp  = (u16*)(ws + alc((size_t)128 * 64 * VPAD * 2));
  float* cost = (float*)(ws + alc((size_t)1024 * 32 * 4));
  float* sint = (float*)(ws + alc((size_t)1024 * 32 * 4));
  (void)ws_size; (void)in_sizes; (void)n_in; (void)out_size;

  // 1. cast x to bf16
  cast_x_kernel<<<4100, 256, 0, stream>>>(x, x_bf, MROWS * 1024 / 8);
  // 2. weights -> K-major bf16
  wt_transpose<<<dim3(16, 16, 4), 256, 0, stream>>>(wq, wk, wv, w_out, wtqkv, wtout);
  // 3. rope tables
  rope_table_kernel<<<128, 256, 0, stream>>>(cost, sint);
  // 4. fused QKV projection: [8200x1024] @ [1024x3072]
  gemm128<0><<<dim3(65, 24), 256, 0, stream>>>(x_bf, wtqkv, (void*)cqkv, nullptr, MROWS, 3072);
  // 5. rope + scale(+log2e) + head split for Q,K
  rope_qk<<<513, 256, 0, stream>>>(cqkv, q_bias, cost, sint, Qhp, Khp);
  // 6. V bias + per-head transpose (zero-padded keys)
  v_transpose<<<dim3(18, 128), 256, 0, stream>>>(cqkv, v_bias, VThp);
  // 7. flash attention (XCD-swizzled 1D grid: 9 q-tiles x 128 bh)
  attn128<<<dim3(1152), 256, 0, stream>>>(Qhp, Khp, VThp, xattn);
  // 8. output projection + bias -> d_out (fp32)
  gemm128<1><<<dim3(65, 8), 256, 0, stream>>>(xattn, wtout, d_out, b_out, MROWS, 1024);
}